// Round 8
// baseline (246.678 us; speedup 1.0000x reference)
//
#include <hip/hip_runtime.h>
#include <math.h>

#define DIM   1024
#define NH    16
#define HD    64
#define GRP   128
#define BB    2
#define TT    2048
#define MROWS (BB*TT)   // 4096

typedef __attribute__((ext_vector_type(8))) short s16x8;
typedef __attribute__((ext_vector_type(4))) float f32x4;
typedef __attribute__((ext_vector_type(4))) int   i32x4;
typedef __attribute__((ext_vector_type(16))) int  i32x16;

__device__ inline float wave_max(float v){
    for(int off=32; off; off>>=1) v = fmaxf(v, __shfl_xor(v, off));
    return v;
}

__device__ inline unsigned short f2bf(float x){
    union { float f; unsigned u; } v; v.f = x;
    unsigned r = v.u + 0x7fffu + ((v.u >> 16) & 1u);
    return (unsigned short)(r >> 16);
}

#if __has_builtin(__builtin_amdgcn_cvt_pk_bf16_f32)
typedef __bf16 bf16x2 __attribute__((ext_vector_type(2)));
__device__ inline unsigned pk2(float a, float b){
    union { bf16x2 v; unsigned u; } c;
    c.v = __builtin_amdgcn_cvt_pk_bf16_f32(a, b);
    return c.u;
}
#else
__device__ inline unsigned pk2(float a, float b){
    return (unsigned)f2bf(a) | ((unsigned)f2bf(b) << 16);
}
#endif

#if __has_builtin(__builtin_amdgcn_exp2f)
__device__ inline float fexp2(float x){ return __builtin_amdgcn_exp2f(x); }
#else
__device__ inline float fexp2(float x){ return exp2f(x); }
#endif

__device__ inline i32x16 zero16(){
    i32x16 z;
    #pragma unroll
    for(int i=0;i<16;i++) z[i]=0;
    return z;
}

__device__ inline void gload16(const void* g, void* l){
    __builtin_amdgcn_global_load_lds((const __attribute__((address_space(1))) unsigned int*)g,
                                     (__attribute__((address_space(3))) unsigned int*)l, 16, 0, 0);
}

#define QSC 0.18033688011112042f   // 0.125 * log2(e)

// ---------------- fused quantization: weights (blocks 0..1023) + activations ----------------
__global__ __launch_bounds__(256) void quant_all(const float* __restrict__ x,
                                                 const float* __restrict__ w0,
                                                 const float* __restrict__ w1,
                                                 const float* __restrict__ w2,
                                                 const float* __restrict__ w3,
                                                 char* __restrict__ w8,
                                                 float* __restrict__ wsall,
                                                 char* __restrict__ xq8,
                                                 float* __restrict__ srow){
    int blk = blockIdx.x;
    int tid = threadIdx.x;
    if (blk < 1024){
        int widx = blk >> 8;
        const float* w = (widx==0)?w0 : (widx==1)?w1 : (widx==2)?w2 : w3;
        int gloc = (blk & 255)*32 + (tid >> 3);
        int j = tid & 7;
        const float* p = w + (size_t)gloc*GRP;
        float r = 0.f;
        #pragma unroll
        for(int i=0;i<16;i++) r += fabsf(p[8*i + j]);
        r += __shfl_xor(r, 1);
        r += __shfl_xor(r, 2);
        r += __shfl_xor(r, 4);
        float ws = r/(float)GRP + 1e-5f;
        if (j == 0) wsall[widx*8192 + gloc] = ws;
        int* q = (int*)(w8 + (size_t)widx*1048576 + (size_t)gloc*GRP);
        int i0 = j*16;
        #pragma unroll
        for(int c4=0;c4<4;c4++){
            float4 v = *(const float4*)(p + i0 + c4*4);
            int b0 = (int)fminf(fmaxf(rintf(v.x/ws),-1.f),1.f);
            int b1 = (int)fminf(fmaxf(rintf(v.y/ws),-1.f),1.f);
            int b2 = (int)fminf(fmaxf(rintf(v.z/ws),-1.f),1.f);
            int b3 = (int)fminf(fmaxf(rintf(v.w/ws),-1.f),1.f);
            q[j*4 + c4] = (b0&0xff) | ((b1&0xff)<<8) | ((b2&0xff)<<16) | ((b3&0xff)<<24);
        }
    } else {
        int row = blk - 1024;
        const float* p = x + (size_t)row*DIM;
        float4 v = *(const float4*)(p + tid*4);
        float m = fmaxf(fmaxf(fabsf(v.x),fabsf(v.y)), fmaxf(fabsf(v.z),fabsf(v.w)));
        m = wave_max(m);
        __shared__ float red[4];
        if ((tid&63)==0) red[tid>>6] = m;
        __syncthreads();
        m = fmaxf(fmaxf(red[0],red[1]), fmaxf(red[2],red[3]));
        float s = 127.f/(m+1e-5f);
        int a0 = (int)fminf(fmaxf(rintf(v.x*s),-128.f),127.f);
        int a1 = (int)fminf(fmaxf(rintf(v.y*s),-128.f),127.f);
        int a2 = (int)fminf(fmaxf(rintf(v.z*s),-128.f),127.f);
        int a3 = (int)fminf(fmaxf(rintf(v.w*s),-128.f),127.f);
        int pk = (a0&0xff) | ((a1&0xff)<<8) | ((a2&0xff)<<16) | ((a3&0xff)<<24);
        ((int*)xq8)[(size_t)row*256 + tid] = pk;
        if (tid==0) srow[row] = s;
    }
}

// ---------------- activation quantization (standalone, for attn output) ----------------
__global__ __launch_bounds__(256) void quant_x_i8(const float* __restrict__ x,
                                                  char* __restrict__ xq8,
                                                  float* __restrict__ srow){
    int row = blockIdx.x;
    int tid = threadIdx.x;
    const float* p = x + (size_t)row*DIM;
    float4 v = *(const float4*)(p + tid*4);
    float m = fmaxf(fmaxf(fabsf(v.x),fabsf(v.y)), fmaxf(fabsf(v.z),fabsf(v.w)));
    m = wave_max(m);
    __shared__ float red[4];
    if ((tid&63)==0) red[tid>>6] = m;
    __syncthreads();
    m = fmaxf(fmaxf(red[0],red[1]), fmaxf(red[2],red[3]));
    float s = 127.f/(m+1e-5f);
    int a0 = (int)fminf(fmaxf(rintf(v.x*s),-128.f),127.f);
    int a1 = (int)fminf(fmaxf(rintf(v.y*s),-128.f),127.f);
    int a2 = (int)fminf(fmaxf(rintf(v.z*s),-128.f),127.f);
    int a3 = (int)fminf(fmaxf(rintf(v.w*s),-128.f),127.f);
    int pk = (a0&0xff) | ((a1&0xff)<<8) | ((a2&0xff)<<16) | ((a3&0xff)<<24);
    ((int*)xq8)[(size_t)row*256 + tid] = pk;
    if (tid==0) srow[row] = s;
}

// ---------------- LDS-free int8 MFMA K-loop (shared by both GEMMs) ----------------
// Each lane loads its mfma_i32_32x32x32_i8 fragments directly from row-major
// global memory (16B aligned). No LDS staging, no barriers -> compiler
// software-pipelines the 96 independent loads with fine-grained vmcnt waits;
// reuse is served by L2 (inputs are 4MB, read 8-64x).
__device__ inline void kloop_i8(const char* __restrict__ Arow,
                                const char* __restrict__ Brow0,
                                const char* __restrict__ Brow1,
                                const float wsr[2][8],
                                float facc[2][16]){
    int lh = (threadIdx.x & 63) >> 5;
    #pragma unroll
    for(int g=0; g<8; g++){
        i32x16 iacc[2];
        iacc[0]=zero16(); iacc[1]=zero16();
        #pragma unroll
        for(int s=0; s<4; s++){
            int off = g*128 + (s*2 + lh)*16;
            i32x4 afr = *(const i32x4*)(Arow  + off);
            i32x4 b0  = *(const i32x4*)(Brow0 + off);
            i32x4 b1  = *(const i32x4*)(Brow1 + off);
            iacc[0] = __builtin_amdgcn_mfma_i32_32x32x32_i8(afr, b0, iacc[0], 0, 0, 0);
            iacc[1] = __builtin_amdgcn_mfma_i32_32x32x32_i8(afr, b1, iacc[1], 0, 0, 0);
        }
        #pragma unroll
        for(int jt=0; jt<2; jt++)
            #pragma unroll
            for(int r=0;r<16;r++)
                facc[jt][r] += (float)iacc[jt][r] * wsr[jt][g];
    }
}

// ---------------- fused QKV int8 GEMM + LDS-staged RoPE/bf16 pack epilogue ----------------
// grid (24, 64): blockIdx.x = widx*8 + n-tile; 64x128 tile.
__global__ __launch_bounds__(256) void gemm_qkv(const char* __restrict__ A8,
                                                const char* __restrict__ w8all,
                                                const float* __restrict__ wsall,
                                                const float* __restrict__ srow,
                                                const float* __restrict__ cosb,
                                                const float* __restrict__ sinb,
                                                unsigned short* __restrict__ Qh,
                                                unsigned short* __restrict__ Kf,
                                                unsigned short* __restrict__ Vf){
    __shared__ float T[64*132];   // 33792 B, epilogue only

    int nt = blockIdx.x;
    int widx = nt >> 3;
    int n0 = (nt & 7)*128;
    int m0 = blockIdx.y*64;
    const char* W8 = w8all + (size_t)widx*1048576;
    const float* wsb = wsall + widx*8192;

    int tid = threadIdx.x;
    int w = tid >> 6, lane = tid & 63;
    int wm = w & 1, wn = w >> 1;
    int l31 = lane & 31, lh = lane >> 5;

    float wsr[2][8];
    #pragma unroll
    for(int jt=0; jt<2; jt++){
        int col = n0 + (wn*2+jt)*32 + l31;
        float4 q0 = *(const float4*)(wsb + (size_t)col*8);
        float4 q1 = *(const float4*)(wsb + (size_t)col*8 + 4);
        wsr[jt][0]=q0.x; wsr[jt][1]=q0.y; wsr[jt][2]=q0.z; wsr[jt][3]=q0.w;
        wsr[jt][4]=q1.x; wsr[jt][5]=q1.y; wsr[jt][6]=q1.z; wsr[jt][7]=q1.w;
    }

    float facc[2][16];
    #pragma unroll
    for(int b=0;b<2;b++)
        #pragma unroll
        for(int r=0;r<16;r++) facc[b][r]=0.f;

    const char* Arow  = A8 + (size_t)(m0 + wm*32 + l31)*1024;
    const char* Brow0 = W8 + (size_t)(n0 + wn*64 + l31)*1024;
    const char* Brow1 = Brow0 + 32*1024;
    kloop_i8(Arow, Brow0, Brow1, wsr, facc);

    // ---- dequant into LDS fp32 tile ----
    #pragma unroll
    for(int r=0; r<16; r++){
        int rowl = wm*32 + (r&3) + 8*(r>>2) + 4*lh;
        float sv = srow[m0 + rowl];
        #pragma unroll
        for(int jt=0; jt<2; jt++){
            int col = (wn*2+jt)*32 + l31;
            T[rowl*132 + col] = facc[jt][r] / sv;
        }
    }
    __syncthreads();

    int kt = (m0 & (TT-1)) >> 6;     // block-uniform key tile
    int bglob = m0 >> 11;            // batch, block-uniform
    int h0 = n0 >> 6;                // first of the 2 heads this block covers

    if (widx == 0){
        // ---- Q: row-order bf16, RoPE + QSC ----
        int row = tid & 63, chunk = tid >> 6;
        int t = (m0 + row) & (TT-1);
        const float* Tr = T + row*132 + chunk*32;
        int colbase = n0 + chunk*32;
        int h = colbase >> 6;
        int d0 = colbase & 63;
        int bh = bglob*NH + h;
        unsigned short* dst = Qh + ((size_t)bh*TT + t)*HD + d0;
        int p0 = d0 >> 1;
        __align__(16) unsigned short ob[32];
        #pragma unroll
        for(int pp=0; pp<16; pp++){
            float c = cosb[t*32 + p0 + pp], s = sinb[t*32 + p0 + pp];
            float e = Tr[2*pp], o = Tr[2*pp+1];
            ob[2*pp]   = f2bf((e*c - o*s)*QSC);
            ob[2*pp+1] = f2bf((e*s + o*c)*QSC);
        }
        #pragma unroll
        for(int c4=0;c4<4;c4++)
            *(s16x8*)(dst + c4*8) = *(s16x8*)(ob + c4*8);
    } else if (widx == 1){
        // ---- K: fragment-order bf16, RoPE ----
        #pragma unroll
        for(int i=0;i<4;i++){
            int e = tid + 256*i;
            int h = e >> 9, e2 = e & 511;
            int f = e2 >> 7, cc = (e2 >> 6)&1, gg = (e2 >> 4)&3, mm = e2 & 15;
            int row = 16*f + mm;
            int t = (m0 + row) & (TT-1);
            int d0 = 8*gg + 32*cc;
            const float* Tr = T + row*132 + h*64 + d0;
            int p0 = d0 >> 1;
            __align__(16) unsigned short ob[8];
            #pragma unroll
            for(int pp=0;pp<4;pp++){
                float c = cosb[t*32 + p0 + pp], s = sinb[t*32 + p0 + pp];
                float ev = Tr[2*pp], ov = Tr[2*pp+1];
                ob[2*pp]   = f2bf(ev*c - ov*s);
                ob[2*pp+1] = f2bf(ev*s + ov*c);
            }
            int bh = bglob*NH + h0 + h;
            size_t entry = ((size_t)(bh*32 + kt))*512 + e2;
            *(s16x8*)(Kf + entry*8) = *(s16x8*)ob;
        }
    } else {
        // ---- V: fragment-order V^T bf16 ----
        #pragma unroll
        for(int i=0;i<4;i++){
            int e = tid + 256*i;
            int h = e >> 9, e2 = e & 511;
            int f = e2 >> 7, cc = (e2 >> 6)&1, gg = (e2 >> 4)&3, mm = e2 & 15;
            int dv = 16*f + mm;
            int tl0 = 8*gg + 32*cc;
            __align__(16) unsigned short ob[8];
            #pragma unroll
            for(int j=0;j<8;j++)
                ob[j] = f2bf(T[(tl0+j)*132 + h*64 + dv]);
            int bh = bglob*NH + h0 + h;
            size_t entry = ((size_t)(bh*32 + kt))*512 + e2;
            *(s16x8*)(Vf + entry*8) = *(s16x8*)ob;
        }
    }
}

// ---------------- LDS-free int8 MFMA GEMM (output projection) ----------------
__global__ __launch_bounds__(256) void gemm_i8(const char* __restrict__ A8,
                                               const char* __restrict__ W8,
                                               const float* __restrict__ wsb,
                                               const float* __restrict__ srow,
                                               float* __restrict__ C){
    int tid = threadIdx.x;
    int w = tid >> 6, lane = tid & 63;
    int wm = w & 1, wn = w >> 1;
    int m0 = blockIdx.y*64, n0 = blockIdx.x*128;
    int l31 = lane & 31, lh = lane >> 5;

    float wsr[2][8];
    #pragma unroll
    for(int jt=0; jt<2; jt++){
        int col = n0 + (wn*2+jt)*32 + l31;
        float4 q0 = *(const float4*)(wsb + (size_t)col*8);
        float4 q1 = *(const float4*)(wsb + (size_t)col*8 + 4);
        wsr[jt][0]=q0.x; wsr[jt][1]=q0.y; wsr[jt][2]=q0.z; wsr[jt][3]=q0.w;
        wsr[jt][4]=q1.x; wsr[jt][5]=q1.y; wsr[jt][6]=q1.z; wsr[jt][7]=q1.w;
    }

    float facc[2][16];
    #pragma unroll
    for(int b=0;b<2;b++)
        #pragma unroll
        for(int r=0;r<16;r++) facc[b][r]=0.f;

    const char* Arow  = A8 + (size_t)(m0 + wm*32 + l31)*1024;
    const char* Brow0 = W8 + (size_t)(n0 + wn*64 + l31)*1024;
    const char* Brow1 = Brow0 + 32*1024;
    kloop_i8(Arow, Brow0, Brow1, wsr, facc);

    #pragma unroll
    for(int r=0; r<16; r++){
        int rowl = wm*32 + (r&3) + 8*(r>>2) + 4*lh;
        float sv = srow[m0 + rowl];
        #pragma unroll
        for(int jt=0; jt<2; jt++){
            int col = n0 + (wn*2+jt)*32 + l31;
            C[(size_t)(m0+rowl)*DIM + col] = facc[jt][r] / sv;
        }
    }
}

// ---------------- MFMA flash attention v3 (verified R5: 57.8 us) ----------------
// 1024 blocks x 256 thr (4 waves), one q-tile (64 rows) per block, globally
// heavy-first. K/V async dbuf (one barrier/tile). Q pre-scaled -> exp2 path.
__global__ __launch_bounds__(256) void attn_mfma3(const unsigned short* __restrict__ Qh,
                                                  const unsigned short* __restrict__ Kf,
                                                  const unsigned short* __restrict__ Vf,
                                                  float* __restrict__ ao){
    __shared__ s16x8 Kbuf[2][512];   // 16 KB
    __shared__ s16x8 Vbuf[2][512];   // 16 KB
    int blk = blockIdx.x;
    int qt = 31 - (blk >> 5);        // heavy first across the whole grid
    int bh = blk & 31;
    int b  = bh >> 4;
    int tid = threadIdx.x;
    int w = tid >> 6, lane = tid & 63;
    int m = lane & 15, g = lane >> 4;
    int q = qt*64 + w*16 + m;

    const unsigned short* Qhead = Qh + (size_t)bh*TT*HD;
    const char* Kbase = (const char*)(Kf + (size_t)bh*32*4096);
    const char* Vbase = (const char*)(Vf + (size_t)bh*32*4096);

    s16x8 Qf0 = *(const s16x8*)(Qhead + (size_t)q*HD + g*8);
    s16x8 Qf1 = *(const s16x8*)(Qhead + (size_t)q*HD + g*8 + 32);

    f32x4 Of[4] = {f32x4{0,0,0,0}, f32x4{0,0,0,0}, f32x4{0,0,0,0}, f32x4{0,0,0,0}};
    float mrow = -1e30f, lrow = 0.f;

    #pragma unroll
    for(int r=0;r<2;r++){
        gload16(Kbase + ((r*4 + w)*64 + lane)*16, (char*)Kbuf[0] + (r*4 + w)*1024);
        gload16(Vbase + ((r*4 + w)*64 + lane)*16, (char*)Vbuf[0] + (r*4 + w)*1024);
    }

    for(int kt=0; kt<=qt; kt++){
        __syncthreads();   // drains loads for buf kt&1
        if (kt < qt){
            int nb = (kt+1)&1;
            size_t goff = (size_t)(kt+1)*8192;
            #pragma unroll
            for(int r=0;r<2;r++){
                gload16(Kbase + goff + ((r*4 + w)*64 + lane)*16, (char*)Kbuf[nb] + (r*4 + w)*1024);
                gload16(Vbase + goff + ((r*4 + w)*64 + lane)*16, (char*)Vbuf[nb] + (r*4 + w)*1024);
            }
        }
        const s16x8* Kc = Kbuf[kt&1];
        const s16x8* Vc = Vbuf[kt&1];

        f32x4 S[4];
        #pragma unroll
        for(int f=0; f<4; f++){
            s16x8 k0 = Kc[(f*2+0)*64 + lane];
            s16x8 k1 = Kc[(f*2+1)*64 + lane];
            f32x4 acc = {0,0,0,0};
            acc = __builtin_amdgcn_mfma_f32_16x16x32_bf16(k0, Qf0, acc, 0, 0, 0);
            acc = __builtin_amdgcn_mfma_f32_16x16x32_bf16(k1, Qf1, acc, 0, 0, 0);
            S[f] = acc;
        }

        float p[4][4];
        float mloc = -1e30f;
        if (kt == qt){
            #pragma unroll
            for(int f=0; f<4; f++)
                #pragma unroll
                for(int r=0; r<4; r++){
                    int key = 16*f + 4*g + r;
                    float s = (qt*64 + key > q) ? -1e30f : S[f][r];
                    p[f][r] = s;
                    mloc = fmaxf(mloc, s);
                }
        } else {
            #pragma unroll
            for(int f=0; f<4; f++)
                #pragma unroll
                for(int r=0; r<4; r++){
                    p[f][r] = S[f][r];
                    mloc = fmaxf(mloc, S[f][r]);
                }
        }
        mloc = fmaxf(mloc, __shfl_xor(mloc, 16));
        mloc = fmaxf(mloc, __shfl_xor(mloc, 32));
        float mn = fmaxf(mrow, mloc);
        float alpha = fexp2(mrow - mn);
        float ps = 0.f;
        #pragma unroll
        for(int f=0; f<4; f++)
            #pragma unroll
            for(int r=0; r<4; r++){
                float e = fexp2(p[f][r] - mn);
                p[f][r] = e;
                ps += e;
            }
        ps += __shfl_xor(ps, 16);
        ps += __shfl_xor(ps, 32);
        lrow = lrow*alpha + ps;
        mrow = mn;

        #pragma unroll
        for(int f2=0; f2<4; f2++)
            #pragma unroll
            for(int r=0; r<4; r++) Of[f2][r] *= alpha;

        unsigned pp0[4], pp1[4];
        #pragma unroll
        for(int f=0; f<4; f++){
            pp0[f] = pk2(p[f][0], p[f][1]);
            pp1[f] = pk2(p[f][2], p[f][3]);
        }

        int src0 = m + 16*(2*(g&1));
        int src1 = src0 + 16;
        bool hi = (g >= 2);
        #pragma unroll
        for(int c=0; c<2; c++){
            unsigned a0 = (unsigned)__shfl((int)pp0[2*c],   src0);
            unsigned a1 = (unsigned)__shfl((int)pp0[2*c+1], src0);
            unsigned b0 = hi ? a1 : a0;
            unsigned a2 = (unsigned)__shfl((int)pp1[2*c],   src0);
            unsigned a3 = (unsigned)__shfl((int)pp1[2*c+1], src0);
            unsigned b1 = hi ? a3 : a2;
            unsigned a4 = (unsigned)__shfl((int)pp0[2*c],   src1);
            unsigned a5 = (unsigned)__shfl((int)pp0[2*c+1], src1);
            unsigned b2 = hi ? a5 : a4;
            unsigned a6 = (unsigned)__shfl((int)pp1[2*c],   src1);
            unsigned a7 = (unsigned)__shfl((int)pp1[2*c+1], src1);
            unsigned b3 = hi ? a7 : a6;
            union { unsigned u[4]; s16x8 v; } Bf;
            Bf.u[0]=b0; Bf.u[1]=b1; Bf.u[2]=b2; Bf.u[3]=b3;
            #pragma unroll
            for(int f2=0; f2<4; f2++){
                s16x8 vf = Vc[(f2*2+c)*64 + lane];
                Of[f2] = __builtin_amdgcn_mfma_f32_16x16x32_bf16(vf, Bf.v, Of[f2], 0, 0, 0);
            }
        }
    }

    float invl = 1.0f / lrow;
    size_t obase = (size_t)(b*TT + q)*DIM + (bh & 15)*HD;
    #pragma unroll
    for(int f2=0; f2<4; f2++)
        #pragma unroll
        for(int r=0; r<4; r++)
            ao[obase + 16*f2 + 4*g + r] = Of[f2][r]*invl;
}

// ---------------- launch ----------------
extern "C" void kernel_launch(void* const* d_in, const int* in_sizes, int n_in,
                              void* d_out, int out_size, void* d_ws, size_t ws_size,
                              hipStream_t stream){
    const float* x    = (const float*)d_in[0];
    const float* cosb = (const float*)d_in[1];
    const float* sinb = (const float*)d_in[2];
    const float* wq_w = (const float*)d_in[3];
    const float* wk_w = (const float*)d_in[4];
    const float* wv_w = (const float*)d_in[5];
    const float* wo_w = (const float*)d_in[6];
    float* out = (float*)d_out;

    char* cw = (char*)d_ws;
    const size_t MB = 1048576;
    char*  w8all = cw;                             // [0,4MB)
    float* wsall = (float*)(cw + 4*MB);            // 128 KB
    float* srow1 = (float*)(cw + 4*MB + 131072);   // 16 KB
    float* srow2 = (float*)(cw + 4*MB + 147456);   // 16 KB
    char*  xq8   = cw + 5*MB;                      // [5,9MB)
    char*  xq8_2 = cw + 9*MB;                      // [9,13MB)
    unsigned short* Qh = (unsigned short*)(cw + 13*MB);  // [13,21MB)
    unsigned short* Kf = (unsigned short*)(cw + 21*MB);  // [21,29MB)
    unsigned short* Vf = (unsigned short*)(cw + 29*MB);  // [29,37MB)
    float* ao    = (float*)(cw + 37*MB);           // [37,53MB)

    quant_all<<<1024 + MROWS, 256, 0, stream>>>(x, wq_w, wk_w, wv_w, wo_w,
                                                w8all, wsall, xq8, srow1);

    gemm_qkv<<<dim3(24, MROWS/64), 256, 0, stream>>>(xq8, w8all, wsall, srow1,
                                                     cosb, sinb, Qh, Kf, Vf);

    attn_mfma3<<<1024, 256, 0, stream>>>(Qh, Kf, Vf, ao);

    quant_x_i8<<<MROWS, 256, 0, stream>>>(ao, xq8_2, srow2);
    gemm_i8<<<dim3(DIM/128, MROWS/64), 256, 0, stream>>>(xq8_2, w8all + 3*MB,
                                                         wsall + 3*8192, srow2, out);
}

// Round 9
// 201.311 us; speedup vs baseline: 1.2254x; 1.2254x over previous
//
#include <hip/hip_runtime.h>
#include <math.h>

#define DIM   1024
#define NH    16
#define HD    64
#define GRP   128
#define BB    2
#define TT    2048
#define MROWS (BB*TT)   // 4096

typedef __attribute__((ext_vector_type(8))) short s16x8;
typedef __attribute__((ext_vector_type(4))) float f32x4;
typedef __attribute__((ext_vector_type(4))) int   i32x4;
typedef __attribute__((ext_vector_type(16))) int  i32x16;

__device__ inline float wave_max(float v){
    for(int off=32; off; off>>=1) v = fmaxf(v, __shfl_xor(v, off));
    return v;
}

__device__ inline unsigned short f2bf(float x){
    union { float f; unsigned u; } v; v.f = x;
    unsigned r = v.u + 0x7fffu + ((v.u >> 16) & 1u);
    return (unsigned short)(r >> 16);
}

#if __has_builtin(__builtin_amdgcn_cvt_pk_bf16_f32)
typedef __bf16 bf16x2 __attribute__((ext_vector_type(2)));
__device__ inline unsigned pk2(float a, float b){
    union { bf16x2 v; unsigned u; } c;
    c.v = __builtin_amdgcn_cvt_pk_bf16_f32(a, b);
    return c.u;
}
#else
__device__ inline unsigned pk2(float a, float b){
    return (unsigned)f2bf(a) | ((unsigned)f2bf(b) << 16);
}
#endif

#if __has_builtin(__builtin_amdgcn_exp2f)
__device__ inline float fexp2(float x){ return __builtin_amdgcn_exp2f(x); }
#else
__device__ inline float fexp2(float x){ return exp2f(x); }
#endif

__device__ inline i32x16 zero16(){
    i32x16 z;
    #pragma unroll
    for(int i=0;i<16;i++) z[i]=0;
    return z;
}

__device__ inline void gload16(const void* g, void* l){
    __builtin_amdgcn_global_load_lds((const __attribute__((address_space(1))) unsigned int*)g,
                                     (__attribute__((address_space(3))) unsigned int*)l, 16, 0, 0);
}

#define QSC 0.18033688011112042f   // 0.125 * log2(e)

// Fragment-order int8 layout: for 32-row block rb, entry ((g*4+s)*64+lane)*16
// holds rows[lane&31], k = g*128 + (s*2 + (lane>>5))*16 .. +15.
// Byte (row, kb) -> rb=row>>5, g=kb>>7, chunk=(kb&127)>>4, s=chunk>>1,
// lane=(chunk&1)*32+(row&31), b16=kb&15.

// ---------------- fused quantization -> fragment-order int8 ----------------
__global__ __launch_bounds__(256) void quant_all(const float* __restrict__ x,
                                                 const float* __restrict__ w0,
                                                 const float* __restrict__ w1,
                                                 const float* __restrict__ w2,
                                                 const float* __restrict__ w3,
                                                 char* __restrict__ wpk,
                                                 float* __restrict__ wsall,
                                                 char* __restrict__ xpk,
                                                 float* __restrict__ srow){
    int blk = blockIdx.x;
    int tid = threadIdx.x;
    if (blk < 1024){
        int widx = blk >> 8;
        const float* w = (widx==0)?w0 : (widx==1)?w1 : (widx==2)?w2 : w3;
        int gloc = (blk & 255)*32 + (tid >> 3);   // group index = n*8 + g
        int j = tid & 7;
        const float* p = w + (size_t)gloc*GRP;
        float r = 0.f;
        #pragma unroll
        for(int i=0;i<16;i++) r += fabsf(p[8*i + j]);
        r += __shfl_xor(r, 1);
        r += __shfl_xor(r, 2);
        r += __shfl_xor(r, 4);
        float ws = r/(float)GRP + 1e-5f;
        if (j == 0) wsall[widx*8192 + gloc] = ws;
        int n = gloc >> 3, g = gloc & 7;
        // fragment-order destination: chunk j -> s=j>>1, lane=(j&1)*32+(n&31)
        char* base = wpk + (size_t)widx*1048576 + (size_t)(n>>5)*32768
                   + (size_t)(((g*4 + (j>>1))*64 + ((j&1)*32 + (n&31)))*16);
        int i0 = j*16;
        #pragma unroll
        for(int c4=0;c4<4;c4++){
            float4 v = *(const float4*)(p + i0 + c4*4);
            int b0 = (int)fminf(fmaxf(rintf(v.x/ws),-1.f),1.f);
            int b1 = (int)fminf(fmaxf(rintf(v.y/ws),-1.f),1.f);
            int b2 = (int)fminf(fmaxf(rintf(v.z/ws),-1.f),1.f);
            int b3 = (int)fminf(fmaxf(rintf(v.w/ws),-1.f),1.f);
            *(int*)(base + c4*4) = (b0&0xff) | ((b1&0xff)<<8) | ((b2&0xff)<<16) | ((b3&0xff)<<24);
        }
    } else {
        int row = blk - 1024;
        const float* p = x + (size_t)row*DIM;
        float4 v = *(const float4*)(p + tid*4);
        float m = fmaxf(fmaxf(fabsf(v.x),fabsf(v.y)), fmaxf(fabsf(v.z),fabsf(v.w)));
        m = wave_max(m);
        __shared__ float red[4];
        if ((tid&63)==0) red[tid>>6] = m;
        __syncthreads();
        m = fmaxf(fmaxf(red[0],red[1]), fmaxf(red[2],red[3]));
        float s = 127.f/(m+1e-5f);
        int a0 = (int)fminf(fmaxf(rintf(v.x*s),-128.f),127.f);
        int a1 = (int)fminf(fmaxf(rintf(v.y*s),-128.f),127.f);
        int a2 = (int)fminf(fmaxf(rintf(v.z*s),-128.f),127.f);
        int a3 = (int)fminf(fmaxf(rintf(v.w*s),-128.f),127.f);
        int pk = (a0&0xff) | ((a1&0xff)<<8) | ((a2&0xff)<<16) | ((a3&0xff)<<24);
        // kb = tid*4: g=tid>>5, chunk=(tid&31)>>2, s=chunk>>1, lane=(chunk&1)*32+(row&31)
        int g = tid >> 5, chunk = (tid&31) >> 2;
        *(int*)(xpk + (size_t)(row>>5)*32768
               + (size_t)(((g*4 + (chunk>>1))*64 + ((chunk&1)*32 + (row&31)))*16)
               + (tid&3)*4) = pk;
        if (tid==0) srow[row] = s;
    }
}

// ---------------- activation quantization -> fragment-order (attn output) ----------------
__global__ __launch_bounds__(256) void quant_x_i8(const float* __restrict__ x,
                                                  char* __restrict__ xpk,
                                                  float* __restrict__ srow){
    int row = blockIdx.x;
    int tid = threadIdx.x;
    const float* p = x + (size_t)row*DIM;
    float4 v = *(const float4*)(p + tid*4);
    float m = fmaxf(fmaxf(fabsf(v.x),fabsf(v.y)), fmaxf(fabsf(v.z),fabsf(v.w)));
    m = wave_max(m);
    __shared__ float red[4];
    if ((tid&63)==0) red[tid>>6] = m;
    __syncthreads();
    m = fmaxf(fmaxf(red[0],red[1]), fmaxf(red[2],red[3]));
    float s = 127.f/(m+1e-5f);
    int a0 = (int)fminf(fmaxf(rintf(v.x*s),-128.f),127.f);
    int a1 = (int)fminf(fmaxf(rintf(v.y*s),-128.f),127.f);
    int a2 = (int)fminf(fmaxf(rintf(v.z*s),-128.f),127.f);
    int a3 = (int)fminf(fmaxf(rintf(v.w*s),-128.f),127.f);
    int pk = (a0&0xff) | ((a1&0xff)<<8) | ((a2&0xff)<<16) | ((a3&0xff)<<24);
    int g = tid >> 5, chunk = (tid&31) >> 2;
    *(int*)(xpk + (size_t)(row>>5)*32768
           + (size_t)(((g*4 + (chunk>>1))*64 + ((chunk&1)*32 + (row&31)))*16)
           + (tid&3)*4) = pk;
    if (tid==0) srow[row] = s;
}

// ---------------- barrier-free int8 MFMA K-loop on fragment-order operands ----------------
// Every load is one coalesced 1KB global_load_dwordx4 per wave; no LDS, no
// barriers; compiler pipelines the 96 independent loads with vmcnt(N).
__device__ inline void kloop_pk(const char* __restrict__ A,
                                const char* __restrict__ B0,
                                const char* __restrict__ B1,
                                const float wsr[2][8],
                                float facc[2][16]){
    int lane = threadIdx.x & 63;
    #pragma unroll
    for(int g=0; g<8; g++){
        i32x16 iacc[2];
        iacc[0]=zero16(); iacc[1]=zero16();
        #pragma unroll
        for(int s=0; s<4; s++){
            size_t off = (size_t)(((g*4+s)*64 + lane)*16);
            i32x4 afr = *(const i32x4*)(A  + off);
            i32x4 b0  = *(const i32x4*)(B0 + off);
            i32x4 b1  = *(const i32x4*)(B1 + off);
            iacc[0] = __builtin_amdgcn_mfma_i32_32x32x32_i8(afr, b0, iacc[0], 0, 0, 0);
            iacc[1] = __builtin_amdgcn_mfma_i32_32x32x32_i8(afr, b1, iacc[1], 0, 0, 0);
        }
        #pragma unroll
        for(int jt=0; jt<2; jt++)
            #pragma unroll
            for(int r=0;r<16;r++)
                facc[jt][r] += (float)iacc[jt][r] * wsr[jt][g];
    }
}

// ---------------- fused QKV int8 GEMM + LDS-staged RoPE/bf16 pack epilogue ----------------
// grid (24, 64): blockIdx.x = widx*8 + n-tile; 64x128 tile.
__global__ __launch_bounds__(256) void gemm_qkv(const char* __restrict__ Apk,
                                                const char* __restrict__ wpk,
                                                const float* __restrict__ wsall,
                                                const float* __restrict__ srow,
                                                const float* __restrict__ cosb,
                                                const float* __restrict__ sinb,
                                                unsigned short* __restrict__ Qh,
                                                unsigned short* __restrict__ Kf,
                                                unsigned short* __restrict__ Vf){
    __shared__ float T[64*132];   // 33792 B, epilogue only

    int nt = blockIdx.x;
    int widx = nt >> 3;
    int n0 = (nt & 7)*128;
    int m0 = blockIdx.y*64;
    const char* W = wpk + (size_t)widx*1048576;
    const float* wsb = wsall + widx*8192;

    int tid = threadIdx.x;
    int w = tid >> 6, lane = tid & 63;
    int wm = w & 1, wn = w >> 1;
    int l31 = lane & 31, lh = lane >> 5;

    float wsr[2][8];
    #pragma unroll
    for(int jt=0; jt<2; jt++){
        int col = n0 + (wn*2+jt)*32 + l31;
        float4 q0 = *(const float4*)(wsb + (size_t)col*8);
        float4 q1 = *(const float4*)(wsb + (size_t)col*8 + 4);
        wsr[jt][0]=q0.x; wsr[jt][1]=q0.y; wsr[jt][2]=q0.z; wsr[jt][3]=q0.w;
        wsr[jt][4]=q1.x; wsr[jt][5]=q1.y; wsr[jt][6]=q1.z; wsr[jt][7]=q1.w;
    }

    float facc[2][16];
    #pragma unroll
    for(int b=0;b<2;b++)
        #pragma unroll
        for(int r=0;r<16;r++) facc[b][r]=0.f;

    const char* A  = Apk + (size_t)((m0>>5) + wm)*32768;
    const char* B0 = W   + (size_t)((n0>>5) + wn*2)*32768;
    const char* B1 = B0 + 32768;
    kloop_pk(A, B0, B1, wsr, facc);

    // ---- dequant into LDS fp32 tile ----
    #pragma unroll
    for(int r=0; r<16; r++){
        int rowl = wm*32 + (r&3) + 8*(r>>2) + 4*lh;
        float sv = srow[m0 + rowl];
        #pragma unroll
        for(int jt=0; jt<2; jt++){
            int col = (wn*2+jt)*32 + l31;
            T[rowl*132 + col] = facc[jt][r] / sv;
        }
    }
    __syncthreads();

    int kt = (m0 & (TT-1)) >> 6;     // block-uniform key tile
    int bglob = m0 >> 11;            // batch, block-uniform
    int h0 = n0 >> 6;                // first of the 2 heads this block covers

    if (widx == 0){
        // ---- Q: row-order bf16, RoPE + QSC ----
        int row = tid & 63, chunk = tid >> 6;
        int t = (m0 + row) & (TT-1);
        const float* Tr = T + row*132 + chunk*32;
        int colbase = n0 + chunk*32;
        int h = colbase >> 6;
        int d0 = colbase & 63;
        int bh = bglob*NH + h;
        unsigned short* dst = Qh + ((size_t)bh*TT + t)*HD + d0;
        int p0 = d0 >> 1;
        __align__(16) unsigned short ob[32];
        #pragma unroll
        for(int pp=0; pp<16; pp++){
            float c = cosb[t*32 + p0 + pp], s = sinb[t*32 + p0 + pp];
            float e = Tr[2*pp], o = Tr[2*pp+1];
            ob[2*pp]   = f2bf((e*c - o*s)*QSC);
            ob[2*pp+1] = f2bf((e*s + o*c)*QSC);
        }
        #pragma unroll
        for(int c4=0;c4<4;c4++)
            *(s16x8*)(dst + c4*8) = *(s16x8*)(ob + c4*8);
    } else if (widx == 1){
        // ---- K: fragment-order bf16, RoPE ----
        #pragma unroll
        for(int i=0;i<4;i++){
            int e = tid + 256*i;
            int h = e >> 9, e2 = e & 511;
            int f = e2 >> 7, cc = (e2 >> 6)&1, gg = (e2 >> 4)&3, mm = e2 & 15;
            int row = 16*f + mm;
            int t = (m0 + row) & (TT-1);
            int d0 = 8*gg + 32*cc;
            const float* Tr = T + row*132 + h*64 + d0;
            int p0 = d0 >> 1;
            __align__(16) unsigned short ob[8];
            #pragma unroll
            for(int pp=0;pp<4;pp++){
                float c = cosb[t*32 + p0 + pp], s = sinb[t*32 + p0 + pp];
                float ev = Tr[2*pp], ov = Tr[2*pp+1];
                ob[2*pp]   = f2bf(ev*c - ov*s);
                ob[2*pp+1] = f2bf(ev*s + ov*c);
            }
            int bh = bglob*NH + h0 + h;
            size_t entry = ((size_t)(bh*32 + kt))*512 + e2;
            *(s16x8*)(Kf + entry*8) = *(s16x8*)ob;
        }
    } else {
        // ---- V: fragment-order V^T bf16 ----
        #pragma unroll
        for(int i=0;i<4;i++){
            int e = tid + 256*i;
            int h = e >> 9, e2 = e & 511;
            int f = e2 >> 7, cc = (e2 >> 6)&1, gg = (e2 >> 4)&3, mm = e2 & 15;
            int dv = 16*f + mm;
            int tl0 = 8*gg + 32*cc;
            __align__(16) unsigned short ob[8];
            #pragma unroll
            for(int j=0;j<8;j++)
                ob[j] = f2bf(T[(tl0+j)*132 + h*64 + dv]);
            int bh = bglob*NH + h0 + h;
            size_t entry = ((size_t)(bh*32 + kt))*512 + e2;
            *(s16x8*)(Vf + entry*8) = *(s16x8*)ob;
        }
    }
}

// ---------------- barrier-free int8 MFMA GEMM (output projection) ----------------
__global__ __launch_bounds__(256) void gemm_i8(const char* __restrict__ Apk,
                                               const char* __restrict__ Wp,
                                               const float* __restrict__ wsb,
                                               const float* __restrict__ srow,
                                               float* __restrict__ C){
    int tid = threadIdx.x;
    int w = tid >> 6, lane = tid & 63;
    int wm = w & 1, wn = w >> 1;
    int m0 = blockIdx.y*64, n0 = blockIdx.x*128;
    int l31 = lane & 31, lh = lane >> 5;

    float wsr[2][8];
    #pragma unroll
    for(int jt=0; jt<2; jt++){
        int col = n0 + (wn*2+jt)*32 + l31;
        float4 q0 = *(const float4*)(wsb + (size_t)col*8);
        float4 q1 = *(const float4*)(wsb + (size_t)col*8 + 4);
        wsr[jt][0]=q0.x; wsr[jt][1]=q0.y; wsr[jt][2]=q0.z; wsr[jt][3]=q0.w;
        wsr[jt][4]=q1.x; wsr[jt][5]=q1.y; wsr[jt][6]=q1.z; wsr[jt][7]=q1.w;
    }

    float facc[2][16];
    #pragma unroll
    for(int b=0;b<2;b++)
        #pragma unroll
        for(int r=0;r<16;r++) facc[b][r]=0.f;

    const char* A  = Apk + (size_t)((m0>>5) + wm)*32768;
    const char* B0 = Wp  + (size_t)((n0>>5) + wn*2)*32768;
    const char* B1 = B0 + 32768;
    kloop_pk(A, B0, B1, wsr, facc);

    #pragma unroll
    for(int r=0; r<16; r++){
        int rowl = wm*32 + (r&3) + 8*(r>>2) + 4*lh;
        float sv = srow[m0 + rowl];
        #pragma unroll
        for(int jt=0; jt<2; jt++){
            int col = n0 + (wn*2+jt)*32 + l31;
            C[(size_t)(m0+rowl)*DIM + col] = facc[jt][r] / sv;
        }
    }
}

// ---------------- MFMA flash attention v3 (verified R5: 57.8 us) ----------------
__global__ __launch_bounds__(256) void attn_mfma3(const unsigned short* __restrict__ Qh,
                                                  const unsigned short* __restrict__ Kf,
                                                  const unsigned short* __restrict__ Vf,
                                                  float* __restrict__ ao){
    __shared__ s16x8 Kbuf[2][512];   // 16 KB
    __shared__ s16x8 Vbuf[2][512];   // 16 KB
    int blk = blockIdx.x;
    int qt = 31 - (blk >> 5);        // heavy first across the whole grid
    int bh = blk & 31;
    int b  = bh >> 4;
    int tid = threadIdx.x;
    int w = tid >> 6, lane = tid & 63;
    int m = lane & 15, g = lane >> 4;
    int q = qt*64 + w*16 + m;

    const unsigned short* Qhead = Qh + (size_t)bh*TT*HD;
    const char* Kbase = (const char*)(Kf + (size_t)bh*32*4096);
    const char* Vbase = (const char*)(Vf + (size_t)bh*32*4096);

    s16x8 Qf0 = *(const s16x8*)(Qhead + (size_t)q*HD + g*8);
    s16x8 Qf1 = *(const s16x8*)(Qhead + (size_t)q*HD + g*8 + 32);

    f32x4 Of[4] = {f32x4{0,0,0,0}, f32x4{0,0,0,0}, f32x4{0,0,0,0}, f32x4{0,0,0,0}};
    float mrow = -1e30f, lrow = 0.f;

    #pragma unroll
    for(int r=0;r<2;r++){
        gload16(Kbase + ((r*4 + w)*64 + lane)*16, (char*)Kbuf[0] + (r*4 + w)*1024);
        gload16(Vbase + ((r*4 + w)*64 + lane)*16, (char*)Vbuf[0] + (r*4 + w)*1024);
    }

    for(int kt=0; kt<=qt; kt++){
        __syncthreads();   // drains loads for buf kt&1
        if (kt < qt){
            int nb = (kt+1)&1;
            size_t goff = (size_t)(kt+1)*8192;
            #pragma unroll
            for(int r=0;r<2;r++){
                gload16(Kbase + goff + ((r*4 + w)*64 + lane)*16, (char*)Kbuf[nb] + (r*4 + w)*1024);
                gload16(Vbase + goff + ((r*4 + w)*64 + lane)*16, (char*)Vbuf[nb] + (r*4 + w)*1024);
            }
        }
        const s16x8* Kc = Kbuf[kt&1];
        const s16x8* Vc = Vbuf[kt&1];

        f32x4 S[4];
        #pragma unroll
        for(int f=0; f<4; f++){
            s16x8 k0 = Kc[(f*2+0)*64 + lane];
            s16x8 k1 = Kc[(f*2+1)*64 + lane];
            f32x4 acc = {0,0,0,0};
            acc = __builtin_amdgcn_mfma_f32_16x16x32_bf16(k0, Qf0, acc, 0, 0, 0);
            acc = __builtin_amdgcn_mfma_f32_16x16x32_bf16(k1, Qf1, acc, 0, 0, 0);
            S[f] = acc;
        }

        float p[4][4];
        float mloc = -1e30f;
        if (kt == qt){
            #pragma unroll
            for(int f=0; f<4; f++)
                #pragma unroll
                for(int r=0; r<4; r++){
                    int key = 16*f + 4*g + r;
                    float s = (qt*64 + key > q) ? -1e30f : S[f][r];
                    p[f][r] = s;
                    mloc = fmaxf(mloc, s);
                }
        } else {
            #pragma unroll
            for(int f=0; f<4; f++)
                #pragma unroll
                for(int r=0; r<4; r++){
                    p[f][r] = S[f][r];
                    mloc = fmaxf(mloc, S[f][r]);
                }
        }
        mloc = fmaxf(mloc, __shfl_xor(mloc, 16));
        mloc = fmaxf(mloc, __shfl_xor(mloc, 32));
        float mn = fmaxf(mrow, mloc);
        float alpha = fexp2(mrow - mn);
        float ps = 0.f;
        #pragma unroll
        for(int f=0; f<4; f++)
            #pragma unroll
            for(int r=0; r<4; r++){
                float e = fexp2(p[f][r] - mn);
                p[f][r] = e;
                ps += e;
            }
        ps += __shfl_xor(ps, 16);
        ps += __shfl_xor(ps, 32);
        lrow = lrow*alpha + ps;
        mrow = mn;

        #pragma unroll
        for(int f2=0; f2<4; f2++)
            #pragma unroll
            for(int r=0; r<4; r++) Of[f2][r] *= alpha;

        unsigned pp0[4], pp1[4];
        #pragma unroll
        for(int f=0; f<4; f++){
            pp0[f] = pk2(p[f][0], p[f][1]);
            pp1[f] = pk2(p[f][2], p[f][3]);
        }

        int src0 = m + 16*(2*(g&1));
        int src1 = src0 + 16;
        bool hi = (g >= 2);
        #pragma unroll
        for(int c=0; c<2; c++){
            unsigned a0 = (unsigned)__shfl((int)pp0[2*c],   src0);
            unsigned a1 = (unsigned)__shfl((int)pp0[2*c+1], src0);
            unsigned b0 = hi ? a1 : a0;
            unsigned a2 = (unsigned)__shfl((int)pp1[2*c],   src0);
            unsigned a3 = (unsigned)__shfl((int)pp1[2*c+1], src0);
            unsigned b1 = hi ? a3 : a2;
            unsigned a4 = (unsigned)__shfl((int)pp0[2*c],   src1);
            unsigned a5 = (unsigned)__shfl((int)pp0[2*c+1], src1);
            unsigned b2 = hi ? a5 : a4;
            unsigned a6 = (unsigned)__shfl((int)pp1[2*c],   src1);
            unsigned a7 = (unsigned)__shfl((int)pp1[2*c+1], src1);
            unsigned b3 = hi ? a7 : a6;
            union { unsigned u[4]; s16x8 v; } Bf;
            Bf.u[0]=b0; Bf.u[1]=b1; Bf.u[2]=b2; Bf.u[3]=b3;
            #pragma unroll
            for(int f2=0; f2<4; f2++){
                s16x8 vf = Vc[(f2*2+c)*64 + lane];
                Of[f2] = __builtin_amdgcn_mfma_f32_16x16x32_bf16(vf, Bf.v, Of[f2], 0, 0, 0);
            }
        }
    }

    float invl = 1.0f / lrow;
    size_t obase = (size_t)(b*TT + q)*DIM + (bh & 15)*HD;
    #pragma unroll
    for(int f2=0; f2<4; f2++)
        #pragma unroll
        for(int r=0; r<4; r++)
            ao[obase + 16*f2 + 4*g + r] = Of[f2][r]*invl;
}

// ---------------- launch ----------------
extern "C" void kernel_launch(void* const* d_in, const int* in_sizes, int n_in,
                              void* d_out, int out_size, void* d_ws, size_t ws_size,
                              hipStream_t stream){
    const float* x    = (const float*)d_in[0];
    const float* cosb = (const float*)d_in[1];
    const float* sinb = (const float*)d_in[2];
    const float* wq_w = (const float*)d_in[3];
    const float* wk_w = (const float*)d_in[4];
    const float* wv_w = (const float*)d_in[5];
    const float* wo_w = (const float*)d_in[6];
    float* out = (float*)d_out;

    char* cw = (char*)d_ws;
    const size_t MB = 1048576;
    char*  wpk   = cw;                             // [0,4MB) fragment-order weights
    float* wsall = (float*)(cw + 4*MB);            // 128 KB
    float* srow1 = (float*)(cw + 4*MB + 131072);   // 16 KB
    float* srow2 = (float*)(cw + 4*MB + 147456);   // 16 KB
    char*  xpk   = cw + 5*MB;                      // [5,9MB)  fragment-order activations
    char*  xpk2  = cw + 9*MB;                      // [9,13MB)
    unsigned short* Qh = (unsigned short*)(cw + 13*MB);  // [13,21MB)
    unsigned short* Kf = (unsigned short*)(cw + 21*MB);  // [21,29MB)
    unsigned short* Vf = (unsigned short*)(cw + 29*MB);  // [29,37MB)
    float* ao    = (float*)(cw + 37*MB);           // [37,53MB)

    quant_all<<<1024 + MROWS, 256, 0, stream>>>(x, wq_w, wk_w, wv_w, wo_w,
                                                wpk, wsall, xpk, srow1);

    gemm_qkv<<<dim3(24, MROWS/64), 256, 0, stream>>>(xpk, wpk, wsall, srow1,
                                                     cosb, sinb, Qh, Kf, Vf);

    attn_mfma3<<<1024, 256, 0, stream>>>(Qh, Kf, Vf, ao);

    quant_x_i8<<<MROWS, 256, 0, stream>>>(ao, xpk2, srow2);
    gemm_i8<<<dim3(DIM/128, MROWS/64), 256, 0, stream>>>(xpk2, wpk + 3*MB,
                                                         wsall + 3*8192, srow2, out);
}